// Round 6
// baseline (792.026 us; speedup 1.0000x reference)
//
#include <hip/hip_runtime.h>
#include <stdint.h>

constexpr int C = 128;
constexpr int F1 = 192;  // C + HID

// ---------------- edge dtype detection ----------------
// If edge_index is true int64 (LE), every odd 4-byte word in the first 2E words
// is a high half of a value < 2^31 => 0. If int32, those words are random node
// ids; finding any nonzero proves int32. res[5] = 1 iff int32 layout.
__global__ void k_detect(const int* __restrict__ ei, int E, int* __restrict__ res) {
    int t = blockIdx.x * 256 + threadIdx.x;
    int idx = 2 * t + 1;                 // odd word; t < 4096 <= E so in bounds
    if (idx < 2 * E && ei[idx] != 0) atomicOr(&res[5], 1);
}

// ---------------- degree ----------------
__global__ void k_deg(const int* __restrict__ ei, int E, const int* __restrict__ res,
                      int* __restrict__ outdeg, int* __restrict__ indeg) {
    int e = blockIdx.x * 256 + threadIdx.x;
    if (e < E) {
        bool i64 = (res[5] == 0);
        int s = i64 ? ei[2 * e]       : ei[e];
        int d = i64 ? ei[2 * (E + e)] : ei[E + e];
        atomicAdd(&outdeg[s], 1);
        atomicAdd(&indeg[d], 1);
    }
}

// ---------------- exclusive scan (3-kernel), with optional fused norm ----------------
__global__ void scan1(const int* __restrict__ in, int* __restrict__ out,
                      int* __restrict__ bsums, int n,
                      const int* __restrict__ outdeg, float* __restrict__ nsrc,
                      float* __restrict__ ndst) {
    __shared__ int sh[1024];
    int i = blockIdx.x * 1024 + threadIdx.x;
    int v = (i < n) ? in[i] : 0;
    // fused degree->norm (first scan only; in == indeg there)
    if (nsrc && i < n) {
        int od = outdeg[i]; if (od < 1) od = 1;
        int id = v;         if (id < 1) id = 1;
        nsrc[i] = (float)(1.0 / sqrt((double)od));
        ndst[i] = (float)(1.0 / sqrt((double)id));
    }
    sh[threadIdx.x] = v;
    __syncthreads();
    for (int off = 1; off < 1024; off <<= 1) {
        int t = (threadIdx.x >= off) ? sh[threadIdx.x - off] : 0;
        __syncthreads();
        sh[threadIdx.x] += t;
        __syncthreads();
    }
    if (i < n) out[i] = sh[threadIdx.x] - v;   // exclusive
    if (threadIdx.x == 1023) bsums[blockIdx.x] = sh[1023];
}

__global__ void scan2(int* __restrict__ bsums, int nb) {
    __shared__ int sh[1024];
    int t = threadIdx.x;
    int v = (t < nb) ? bsums[t] : 0;
    sh[t] = v;
    __syncthreads();
    for (int off = 1; off < 1024; off <<= 1) {
        int u = (t >= off) ? sh[t - off] : 0;
        __syncthreads();
        sh[t] += u;
        __syncthreads();
    }
    if (t < nb) bsums[t] = sh[t] - v;          // exclusive block offsets
}

__global__ void scan3(int* __restrict__ data, const int* __restrict__ bsums,
                      int* __restrict__ copy2, int n) {
    int i = blockIdx.x * 1024 + threadIdx.x;
    if (i < n) {
        int v = data[i] + bsums[blockIdx.x];
        data[i] = v;
        if (copy2) copy2[i] = v;
    }
}

// ---------------- CSR build (by dst) ----------------
__global__ void k_csr(const int* __restrict__ ei, int E, const int* __restrict__ res,
                      int* __restrict__ cursor, int* __restrict__ csr) {
    int e = blockIdx.x * 256 + threadIdx.x;
    if (e < E) {
        bool i64 = (res[5] == 0);
        int s = i64 ? ei[2 * e]       : ei[e];
        int d = i64 ? ei[2 * (E + e)] : ei[E + e];
        int p = atomicAdd(&cursor[d], 1);
        csr[p] = s;
    }
}

// ---------------- layer-1 aggregation: one wave per node ----------------
// g[n][:] = ndst[n] * sum_{s in sorted in-neighbors} x[s][:]*nsrc[s]
// Neighbor list sorted in-wave (deg-iter rank, wave-uniform deg) and written
// back so every replay sums in identical order -> deterministic scores.
__global__ __launch_bounds__(256) void k_agg(const float* __restrict__ x,
        int* __restrict__ csr, const int* __restrict__ indeg,
        const int* __restrict__ offsets, const float* __restrict__ nsrc,
        const float* __restrict__ ndst, float* __restrict__ g, int N) {
    int wid  = (blockIdx.x * 256 + threadIdx.x) >> 6;  // node id (wave-uniform)
    int lane = threadIdx.x & 63;
    if (wid >= N) return;
    int deg = indeg[wid];
    int off = offsets[wid];
    float acc0 = 0.f, acc1 = 0.f;
    if (deg > 0 && deg <= 64) {
        int v = (lane < deg) ? csr[off + lane] : 0x7fffffff;
        int rank = 0;
        for (int j = 0; j < deg; ++j) {                  // deg iters, not 64
            int vj = __builtin_amdgcn_readlane(v, j);    // SGPR broadcast
            rank += (vj < v) || (vj == v && j < lane);
        }
        int sv = __builtin_amdgcn_ds_permute(rank << 2, v);  // push v to lane 'rank'
        if (lane < deg) csr[off + lane] = sv;                // sorted write-back for k_l2
        float nsv = (lane < deg) ? nsrc[sv] : 0.f;           // prefetch all norms
        int nsb = __float_as_int(nsv);
        for (int i = 0; i < deg; ++i) {
            int s    = __builtin_amdgcn_readlane(sv, i);               // SGPR
            float ns = __int_as_float(__builtin_amdgcn_readlane(nsb, i));
            float2 xr = ((const float2*)x)[(size_t)s * 64 + lane];     // 512B coalesced
            acc0 = fmaf(xr.x, ns, acc0);
            acc1 = fmaf(xr.y, ns, acc1);
        }
    } else if (deg > 64) {   // Poisson(8) tail: ~impossible; correct, unsorted
        for (int i = 0; i < deg; ++i) {
            int s = csr[off + i];
            float ns = nsrc[s];
            float2 xr = ((const float2*)x)[(size_t)s * 64 + lane];
            acc0 = fmaf(xr.x, ns, acc0);
            acc1 = fmaf(xr.y, ns, acc1);
        }
    }
    float nd = ndst[wid];
    ((float2*)g)[(size_t)wid * 64 + lane] = make_float2(acc0 * nd, acc1 * nd);
}

// ---------------- fused GEMM + ReLU + dot(W2) ----------------
// tn[n] = nsrc[n] * sum_j relu(b1[j] + sum_c g[n][c]*W1[c][j]) * W2[j]
// Tile: 128 nodes/block; 256 threads = 128 nodes x 2 j-halves (96 j each).
// g rows live in LDS (64KB), XOR-swizzled per 16B slot (slot ^= node&7) so a
// wave's ds_read_b128 at row-stride 512B hits every bank exactly 8x (uniform,
// conflict-free). acc[16] per j-block stays in VGPRs -> nothing to spill
// (round-4 failure: r[128] demoted to scratch, VGPR_Count=72, 207us).
// W1 is read as wave-broadcast float4 loads (same addr across lanes -> 1 L1
// line each); no reliance on scalar-load uniformity analysis.
// launch_bounds(256,2): occupancy is LDS-bound at 2 blocks/CU regardless, so
// cap VGPRs at 256 (not 128) to guarantee the unrolled inner loop never spills.
__global__ __launch_bounds__(256, 2) void k_gemm(const float* __restrict__ g,
        const float* __restrict__ W1, const float* __restrict__ b1,
        const float* __restrict__ W2, const float* __restrict__ nsrc,
        float* __restrict__ tn, int N) {
    __shared__ float sA[128 * 128];          // 64 KB
    int t = threadIdx.x;
    int r = t & 127;                          // node row in tile
    int h = t >> 7;                           // stage: k-half; compute: j-half
    int node = blockIdx.x * 128 + r;
    // ---- stage g rows -> LDS (swizzled slots) ----
    const float4* grow = (const float4*)(g + (size_t)node * 128);
    #pragma unroll
    for (int i = 0; i < 16; ++i) {
        int k0 = h * 16 + i;                 // 16B slot index 0..31
        float4 v = (node < N) ? grow[k0] : make_float4(0.f, 0.f, 0.f, 0.f);
        int slot = k0 ^ (r & 7);
        *(float4*)&sA[r * 128 + slot * 4] = v;
    }
    __syncthreads();
    // ---- compute 96 outputs (j-half h) in 6 blocks of 16 ----
    float tp = 0.f;
    #pragma unroll 1
    for (int jb = 0; jb < 6; ++jb) {
        int j0 = h * 96 + jb * 16;
        float acc[16];
        #pragma unroll
        for (int jj = 0; jj < 16; ++jj) acc[jj] = b1[j0 + jj];
        #pragma unroll 2
        for (int k0 = 0; k0 < 32; ++k0) {    // 4 k per iteration
            float4 av = *(const float4*)&sA[r * 128 + ((k0 ^ (r & 7)) << 2)];
            float a4[4] = {av.x, av.y, av.z, av.w};
            #pragma unroll
            for (int q = 0; q < 4; ++q) {
                const float* wr = W1 + (4 * k0 + q) * 192 + j0;
                float4 w0 = *(const float4*)(wr + 0);
                float4 w1 = *(const float4*)(wr + 4);
                float4 w2 = *(const float4*)(wr + 8);
                float4 w3 = *(const float4*)(wr + 12);
                float aq = a4[q];
                acc[ 0] = fmaf(aq, w0.x, acc[ 0]);
                acc[ 1] = fmaf(aq, w0.y, acc[ 1]);
                acc[ 2] = fmaf(aq, w0.z, acc[ 2]);
                acc[ 3] = fmaf(aq, w0.w, acc[ 3]);
                acc[ 4] = fmaf(aq, w1.x, acc[ 4]);
                acc[ 5] = fmaf(aq, w1.y, acc[ 5]);
                acc[ 6] = fmaf(aq, w1.z, acc[ 6]);
                acc[ 7] = fmaf(aq, w1.w, acc[ 7]);
                acc[ 8] = fmaf(aq, w2.x, acc[ 8]);
                acc[ 9] = fmaf(aq, w2.y, acc[ 9]);
                acc[10] = fmaf(aq, w2.z, acc[10]);
                acc[11] = fmaf(aq, w2.w, acc[11]);
                acc[12] = fmaf(aq, w3.x, acc[12]);
                acc[13] = fmaf(aq, w3.y, acc[13]);
                acc[14] = fmaf(aq, w3.z, acc[14]);
                acc[15] = fmaf(aq, w3.w, acc[15]);
            }
        }
        #pragma unroll
        for (int jj = 0; jj < 16; ++jj)
            tp = fmaf(fmaxf(acc[jj], 0.f), W2[j0 + jj], tp);
    }
    // ---- combine the two j-halves via LDS (reuse sA) ----
    __syncthreads();
    sA[t] = tp;
    __syncthreads();
    if (t < 128 && node < N) tn[node] = (sA[t] + sA[t + 128]) * nsrc[node];
}

// ---------------- layer-2 scalar aggregation + |score| bits + histogram ----------------
// W2 commutes past the aggregation: per-edge payload is ONE float, not 192.
__global__ void k_l2(const int* __restrict__ csr, const int* __restrict__ indeg,
                     const int* __restrict__ offsets, const float* __restrict__ tn,
                     const float* __restrict__ ndst, const float* __restrict__ b2,
                     unsigned int* __restrict__ U, int* __restrict__ hist1, int N) {
    int n = blockIdx.x * 256 + threadIdx.x;
    if (n >= N) return;
    int deg = indeg[n], off = offsets[n];
    float s = 0.f;
    for (int i = 0; i < deg; ++i) s += tn[csr[off + i]];   // sorted order -> deterministic
    float sc = ndst[n] * s + b2[0];
    unsigned int u = __float_as_uint(fabsf(sc));           // monotonic for non-negative floats
    U[n] = u;
    atomicAdd(&hist1[u >> 16], 1);
}

// ---------------- radix-select pass 1: high 16 bits ----------------
__global__ void k_findbin1(const int* __restrict__ hist, int k, int* __restrict__ res) {
    __shared__ int sh[1024];
    int t = threadIdx.x;
    int base = 65535 - 64 * t;      // chunk t covers 64 bins, high->low
    int s = 0;
    for (int q = 0; q < 64; ++q) s += hist[base - q];
    sh[t] = s;
    __syncthreads();
    int v = s;
    for (int off = 1; off < 1024; off <<= 1) {
        int u = (t >= off) ? sh[t - off] : 0;
        __syncthreads();
        sh[t] += u;
        __syncthreads();
    }
    int before = sh[t] - v;          // elements in all bins above this chunk
    if (before < k && sh[t] >= k) {
        int cum = before;
        for (int q = 0; q < 64; ++q) {
            int b = base - q;
            int hh = hist[b];
            if (cum + hh >= k) { res[0] = b; res[1] = k - cum; break; }
            cum += hh;
        }
    }
}

__global__ void k_hist2(const unsigned int* __restrict__ U, const int* __restrict__ res,
                        int* __restrict__ hist2, int N) {
    int n = blockIdx.x * 256 + threadIdx.x;
    if (n < N) {
        unsigned int u = U[n];
        if ((int)(u >> 16) == res[0]) atomicAdd(&hist2[u & 0xffff], 1);
    }
}

// ---------------- radix-select pass 2: low 16 bits ----------------
__global__ void k_findbin2(const int* __restrict__ hist, int* __restrict__ res) {
    __shared__ int sh[1024];
    int k = res[1];
    int t = threadIdx.x;
    int base = 65535 - 64 * t;
    int s = 0;
    for (int q = 0; q < 64; ++q) s += hist[base - q];
    sh[t] = s;
    __syncthreads();
    int v = s;
    for (int off = 1; off < 1024; off <<= 1) {
        int u = (t >= off) ? sh[t - off] : 0;
        __syncthreads();
        sh[t] += u;
        __syncthreads();
    }
    int before = sh[t] - v;
    if (before < k && sh[t] >= k) {
        int cum = before;
        for (int q = 0; q < 64; ++q) {
            int b = base - q;
            int hh = hist[b];
            if (cum + hh >= k) {
                res[2] = (int)(((unsigned int)res[0] << 16) | (unsigned int)b);  // threshold bits
                res[3] = k - cum;                                                // # ties to keep
                break;
            }
            cum += hh;
        }
    }
}

// ---------------- selection flags (+ tie collection) ----------------
__global__ void k_flags(const unsigned int* __restrict__ U, int* __restrict__ res,
                        int* __restrict__ sel, int* __restrict__ tielist, int N) {
    int n = blockIdx.x * 256 + threadIdx.x;
    if (n >= N) return;
    unsigned int T = (unsigned int)res[2];
    unsigned int u = U[n];
    sel[n] = (u > T) ? 1 : 0;
    if (u == T) {
        int p = atomicAdd(&res[4], 1);
        if (p < 4096) tielist[p] = n;
    }
}

// ties: keep the res[3] ties with smallest node index (jax top_k stability:
// equal values ranked by ascending index)
__global__ void k_ties(const int* __restrict__ res, int* __restrict__ tielist,
                       int* __restrict__ sel) {
    if (threadIdx.x != 0) return;
    int cnt = res[4]; if (cnt > 4096) cnt = 4096;
    int need = res[3]; if (need > cnt) need = cnt;
    for (int r = 0; r < need; ++r) {
        int mi = 0, mv = 0x7fffffff;
        for (int i = 0; i < cnt; ++i) {
            int v = tielist[i];
            if (v < mv) { mv = v; mi = i; }
        }
        sel[mv] = 1;
        tielist[mi] = 0x7fffffff;
    }
}

// ---------------- compact rows: one wave per node ----------------
__global__ __launch_bounds__(256) void k_out(const float* __restrict__ x,
        const int* __restrict__ sel, const int* __restrict__ pos,
        float* __restrict__ out, int N) {
    int wid  = (blockIdx.x * 256 + threadIdx.x) >> 6;
    int lane = threadIdx.x & 63;
    if (wid >= N) return;
    if (sel[wid]) {
        int p = pos[wid];
        ((float2*)out)[(size_t)p * 64 + lane] = ((const float2*)x)[(size_t)wid * 64 + lane];
    }
}

extern "C" void kernel_launch(void* const* d_in, const int* in_sizes, int n_in,
                              void* d_out, int out_size, void* d_ws, size_t ws_size,
                              hipStream_t stream) {
    const float* x  = (const float*)d_in[0];
    const int*   ei = (const int*)d_in[1];
    const float* W1 = (const float*)d_in[2];
    const float* b1 = (const float*)d_in[3];
    const float* W2 = (const float*)d_in[4];
    const float* b2 = (const float*)d_in[5];
    int N = in_sizes[0] / C;            // 100000
    int E = in_sizes[1] / 2;            // 800000 (element count, dtype-independent)
    int k = out_size / C;               // harness-derived k: exact, no float repro risk

    char* w = (char*)d_ws;
    size_t ofs = 0;
    auto alloc = [&](size_t bytes) -> char* {
        char* p = w + ofs;
        ofs += (bytes + 511) & ~(size_t)511;
        return p;
    };
    // zero-init region first (single contiguous memset)
    int*   outdeg  = (int*)alloc((size_t)N * 4);
    int*   indeg   = (int*)alloc((size_t)N * 4);
    int*   hist1   = (int*)alloc(65536 * 4);
    int*   hist2   = (int*)alloc(65536 * 4);
    int*   res     = (int*)alloc(64);
    size_t zero_bytes = ofs;
    // rest (fully overwritten before use)
    int*   offsets = (int*)alloc((size_t)(N + 1) * 4);
    int*   cursor  = (int*)alloc((size_t)N * 4);
    int*   csr     = (int*)alloc((size_t)E * 4);
    float* nsrc    = (float*)alloc((size_t)N * 4);
    float* ndst    = (float*)alloc((size_t)N * 4);
    float* g       = (float*)alloc((size_t)N * C * 4);
    float* tn      = (float*)alloc((size_t)N * 4);
    unsigned int* U = (unsigned int*)alloc((size_t)N * 4);
    int*   tielist = (int*)alloc(4096 * 4);
    int*   sel     = (int*)alloc((size_t)N * 4);
    int*   pos     = (int*)alloc((size_t)N * 4);
    int*   bsums   = (int*)alloc(1024 * 4);

    hipMemsetAsync(d_ws, 0, zero_bytes, stream);

    int nb = (N + 1023) / 1024;
    k_detect<<<16, 256, 0, stream>>>(ei, E, res);
    k_deg<<<(E + 255) / 256, 256, 0, stream>>>(ei, E, res, outdeg, indeg);
    scan1<<<nb, 1024, 0, stream>>>(indeg, offsets, bsums, N, outdeg, nsrc, ndst);
    scan2<<<1, 1024, 0, stream>>>(bsums, nb);
    scan3<<<nb, 1024, 0, stream>>>(offsets, bsums, cursor, N);
    k_csr<<<(E + 255) / 256, 256, 0, stream>>>(ei, E, res, cursor, csr);
    k_agg<<<(N + 3) / 4, 256, 0, stream>>>(x, csr, indeg, offsets, nsrc, ndst, g, N);
    k_gemm<<<(N + 127) / 128, 256, 0, stream>>>(g, W1, b1, W2, nsrc, tn, N);
    k_l2<<<(N + 255) / 256, 256, 0, stream>>>(csr, indeg, offsets, tn, ndst, b2, U, hist1, N);
    k_findbin1<<<1, 1024, 0, stream>>>(hist1, k, res);
    k_hist2<<<(N + 255) / 256, 256, 0, stream>>>(U, res, hist2, N);
    k_findbin2<<<1, 1024, 0, stream>>>(hist2, res);
    k_flags<<<(N + 255) / 256, 256, 0, stream>>>(U, res, sel, tielist, N);
    k_ties<<<1, 64, 0, stream>>>(res, tielist, sel);
    scan1<<<nb, 1024, 0, stream>>>(sel, pos, bsums, N, nullptr, nullptr, nullptr);
    scan2<<<1, 1024, 0, stream>>>(bsums, nb);
    scan3<<<nb, 1024, 0, stream>>>(pos, bsums, nullptr, N);
    k_out<<<(N + 3) / 4, 256, 0, stream>>>(x, sel, pos, (float*)d_out, N);
}

// Round 7
// 481.036 us; speedup vs baseline: 1.6465x; 1.6465x over previous
//
#include <hip/hip_runtime.h>
#include <stdint.h>

constexpr int C = 128;
constexpr int F1 = 192;  // C + HID

// ---------------- edge dtype detection ----------------
__global__ void k_detect(const int* __restrict__ ei, int E, int* __restrict__ res) {
    int t = blockIdx.x * 256 + threadIdx.x;
    int idx = 2 * t + 1;                 // odd word; t < 4096 <= E so in bounds
    if (idx < 2 * E && ei[idx] != 0) atomicOr(&res[5], 1);
}

// ---------------- degree ----------------
__global__ void k_deg(const int* __restrict__ ei, int E, const int* __restrict__ res,
                      int* __restrict__ outdeg, int* __restrict__ indeg) {
    int e = blockIdx.x * 256 + threadIdx.x;
    if (e < E) {
        bool i64 = (res[5] == 0);
        int s = i64 ? ei[2 * e]       : ei[e];
        int d = i64 ? ei[2 * (E + e)] : ei[E + e];
        atomicAdd(&outdeg[s], 1);
        atomicAdd(&indeg[d], 1);
    }
}

// ---------------- exclusive scan (3-kernel), with optional fused norm ----------------
__global__ void scan1(const int* __restrict__ in, int* __restrict__ out,
                      int* __restrict__ bsums, int n,
                      const int* __restrict__ outdeg, float* __restrict__ nsrc,
                      float* __restrict__ ndst) {
    __shared__ int sh[1024];
    int i = blockIdx.x * 1024 + threadIdx.x;
    int v = (i < n) ? in[i] : 0;
    if (nsrc && i < n) {
        int od = outdeg[i]; if (od < 1) od = 1;
        int id = v;         if (id < 1) id = 1;
        nsrc[i] = (float)(1.0 / sqrt((double)od));
        ndst[i] = (float)(1.0 / sqrt((double)id));
    }
    sh[threadIdx.x] = v;
    __syncthreads();
    for (int off = 1; off < 1024; off <<= 1) {
        int t = (threadIdx.x >= off) ? sh[threadIdx.x - off] : 0;
        __syncthreads();
        sh[threadIdx.x] += t;
        __syncthreads();
    }
    if (i < n) out[i] = sh[threadIdx.x] - v;   // exclusive
    if (threadIdx.x == 1023) bsums[blockIdx.x] = sh[1023];
}

__global__ void scan2(int* __restrict__ bsums, int nb) {
    __shared__ int sh[1024];
    int t = threadIdx.x;
    int v = (t < nb) ? bsums[t] : 0;
    sh[t] = v;
    __syncthreads();
    for (int off = 1; off < 1024; off <<= 1) {
        int u = (t >= off) ? sh[t - off] : 0;
        __syncthreads();
        sh[t] += u;
        __syncthreads();
    }
    if (t < nb) bsums[t] = sh[t] - v;          // exclusive block offsets
}

__global__ void scan3(int* __restrict__ data, const int* __restrict__ bsums,
                      int* __restrict__ copy2, int n) {
    int i = blockIdx.x * 1024 + threadIdx.x;
    if (i < n) {
        int v = data[i] + bsums[blockIdx.x];
        data[i] = v;
        if (copy2) copy2[i] = v;
    }
}

// ---------------- CSR build (by dst) ----------------
__global__ void k_csr(const int* __restrict__ ei, int E, const int* __restrict__ res,
                      int* __restrict__ cursor, int* __restrict__ csr) {
    int e = blockIdx.x * 256 + threadIdx.x;
    if (e < E) {
        bool i64 = (res[5] == 0);
        int s = i64 ? ei[2 * e]       : ei[e];
        int d = i64 ? ei[2 * (E + e)] : ei[E + e];
        int p = atomicAdd(&cursor[d], 1);
        csr[p] = s;
    }
}

// ---------------- layer-1 aggregation: one wave per node ----------------
__global__ __launch_bounds__(256) void k_agg(const float* __restrict__ x,
        int* __restrict__ csr, const int* __restrict__ indeg,
        const int* __restrict__ offsets, const float* __restrict__ nsrc,
        const float* __restrict__ ndst, float* __restrict__ g, int N) {
    int wid  = (blockIdx.x * 256 + threadIdx.x) >> 6;  // node id (wave-uniform)
    int lane = threadIdx.x & 63;
    if (wid >= N) return;
    int deg = indeg[wid];
    int off = offsets[wid];
    float acc0 = 0.f, acc1 = 0.f;
    if (deg > 0 && deg <= 64) {
        int v = (lane < deg) ? csr[off + lane] : 0x7fffffff;
        int rank = 0;
        for (int j = 0; j < deg; ++j) {
            int vj = __builtin_amdgcn_readlane(v, j);
            rank += (vj < v) || (vj == v && j < lane);
        }
        int sv = __builtin_amdgcn_ds_permute(rank << 2, v);
        if (lane < deg) csr[off + lane] = sv;                // sorted write-back for k_l2
        float nsv = (lane < deg) ? nsrc[sv] : 0.f;
        int nsb = __float_as_int(nsv);
        int i = 0;
        for (; i + 1 < deg; i += 2) {                        // unroll-2: 2 loads in flight
            int   s0 = __builtin_amdgcn_readlane(sv, i);
            int   s1 = __builtin_amdgcn_readlane(sv, i + 1);
            float n0 = __int_as_float(__builtin_amdgcn_readlane(nsb, i));
            float n1 = __int_as_float(__builtin_amdgcn_readlane(nsb, i + 1));
            float2 x0 = ((const float2*)x)[(size_t)s0 * 64 + lane];
            float2 x1 = ((const float2*)x)[(size_t)s1 * 64 + lane];
            acc0 = fmaf(x0.x, n0, acc0);
            acc1 = fmaf(x0.y, n0, acc1);
            acc0 = fmaf(x1.x, n1, acc0);
            acc1 = fmaf(x1.y, n1, acc1);
        }
        if (i < deg) {
            int   s0 = __builtin_amdgcn_readlane(sv, i);
            float n0 = __int_as_float(__builtin_amdgcn_readlane(nsb, i));
            float2 x0 = ((const float2*)x)[(size_t)s0 * 64 + lane];
            acc0 = fmaf(x0.x, n0, acc0);
            acc1 = fmaf(x0.y, n0, acc1);
        }
    } else if (deg > 64) {
        for (int i = 0; i < deg; ++i) {
            int s = csr[off + i];
            float ns = nsrc[s];
            float2 xr = ((const float2*)x)[(size_t)s * 64 + lane];
            acc0 = fmaf(xr.x, ns, acc0);
            acc1 = fmaf(xr.y, ns, acc1);
        }
    }
    float nd = ndst[wid];
    ((float2*)g)[(size_t)wid * 64 + lane] = make_float2(acc0 * nd, acc1 * nd);
}

// ---------------- fused GEMM + ReLU + dot(W2): register-blocked LDS GEMM ----------------
// Block: 128 nodes x 192 j; 256 threads = 16 node-groups x 16 j-groups; thread
// tile 8x12 = 96 acc (VGPR-resident; round-4 lesson: big arrays get scratch-
// demoted). K in 4 steps of 32.
//  At[32][132] (pad-132): global g loads 128B-coalesced (kq=T&7); staging b32
//    writes 4-way ((16kq+4w+node)%32 spans 16 banks); compute reads are 16-lane
//    broadcasts to 4 disjoint bank-quads -> conflict-free.
//  Wt[32][200] (pad-200): staging fully coalesced from W1; compute b128 reads
//    at jg*12 stride cover all 32 banks <=2 addrs each -> free. Staging b128
//    writes are 8-way but only 6/thread/K-step (~3% of compute) -> accepted.
// Round-6 lesson: NO wave-uniform W loads (scalarized into serialized s_load
// chains, 917k cyc); W goes through LDS like A.
__global__ __launch_bounds__(256, 3) void k_gemm(const float* __restrict__ g,
        const float* __restrict__ W1, const float* __restrict__ b1,
        const float* __restrict__ W2, const float* __restrict__ nsrc,
        float* __restrict__ tn, int N) {
    __shared__ float At[32 * 132];   // 16.9 KB
    __shared__ float Wt[32 * 200];   // 25.6 KB  -> 42.5 KB total, 3 blocks/CU
    int T  = threadIdx.x;
    int ng = T >> 4, jg = T & 15;
    int nb = blockIdx.x * 128;
    float acc[8][12];
    #pragma unroll
    for (int jj = 0; jj < 12; ++jj) {
        float b = b1[jg * 12 + jj];
        #pragma unroll
        for (int i = 0; i < 8; ++i) acc[i][jj] = b;
    }
    for (int s = 0; s < 4; ++s) {
        int k0 = s * 32;
        if (s) __syncthreads();          // previous step's reads done before overwrite
        // ---- stage A (transposed, pad-132) ----
        int kq = T & 7;
        #pragma unroll
        for (int t = 0; t < 4; ++t) {
            int nl = (T >> 3) + 32 * t;
            int node = nb + nl;
            float4 v = make_float4(0.f, 0.f, 0.f, 0.f);
            if (node < N) v = *(const float4*)(g + (size_t)node * 128 + k0 + kq * 4);
            int base = (kq * 4) * 132 + nl;
            At[base]       = v.x;
            At[base + 132] = v.y;
            At[base + 264] = v.z;
            At[base + 396] = v.w;
        }
        // ---- stage W (row-major, pad-200) ----
        #pragma unroll
        for (int i = 0; i < 6; ++i) {
            int idx = i * 256 + T;
            int r = idx / 48, j4 = idx - r * 48;
            float4 v = *(const float4*)(W1 + (k0 + r) * 192 + j4 * 4);
            *(float4*)&Wt[r * 200 + j4 * 4] = v;
        }
        __syncthreads();
        // ---- compute: 32 kk x (2+3 b128 reads, 96 fma) ----
        for (int kk = 0; kk < 32; ++kk) {
            float4 a0 = *(const float4*)&At[kk * 132 + ng * 8];
            float4 a1 = *(const float4*)&At[kk * 132 + ng * 8 + 4];
            float4 w0 = *(const float4*)&Wt[kk * 200 + jg * 12];
            float4 w1 = *(const float4*)&Wt[kk * 200 + jg * 12 + 4];
            float4 w2 = *(const float4*)&Wt[kk * 200 + jg * 12 + 8];
            float a[8]  = {a0.x, a0.y, a0.z, a0.w, a1.x, a1.y, a1.z, a1.w};
            float w[12] = {w0.x, w0.y, w0.z, w0.w, w1.x, w1.y, w1.z, w1.w,
                           w2.x, w2.y, w2.z, w2.w};
            #pragma unroll
            for (int i = 0; i < 8; ++i) {
                #pragma unroll
                for (int jj = 0; jj < 12; ++jj)
                    acc[i][jj] = fmaf(a[i], w[jj], acc[i][jj]);
            }
        }
    }
    // ---- epilogue: relu . W2, 16-lane butterfly per node, store tn ----
    float w2r[12];
    #pragma unroll
    for (int jj = 0; jj < 12; ++jj) w2r[jj] = W2[jg * 12 + jj];
    #pragma unroll
    for (int i = 0; i < 8; ++i) {
        float p = 0.f;
        #pragma unroll
        for (int jj = 0; jj < 12; ++jj) p = fmaf(fmaxf(acc[i][jj], 0.f), w2r[jj], p);
        p += __shfl_xor(p, 1);
        p += __shfl_xor(p, 2);
        p += __shfl_xor(p, 4);
        p += __shfl_xor(p, 8);
        if (jg == 0) {
            int node = nb + ng * 8 + i;
            if (node < N) tn[node] = p * nsrc[node];
        }
    }
}

// ---------------- layer-2 scalar aggregation + |score| bits + histogram ----------------
__global__ void k_l2(const int* __restrict__ csr, const int* __restrict__ indeg,
                     const int* __restrict__ offsets, const float* __restrict__ tn,
                     const float* __restrict__ ndst, const float* __restrict__ b2,
                     unsigned int* __restrict__ U, int* __restrict__ hist1, int N) {
    int n = blockIdx.x * 256 + threadIdx.x;
    if (n >= N) return;
    int deg = indeg[n], off = offsets[n];
    float s = 0.f;
    for (int i = 0; i < deg; ++i) s += tn[csr[off + i]];   // sorted order -> deterministic
    float sc = ndst[n] * s + b2[0];
    unsigned int u = __float_as_uint(fabsf(sc));
    U[n] = u;
    atomicAdd(&hist1[u >> 16], 1);
}

// ---------------- radix-select pass 1: high 16 bits ----------------
__global__ void k_findbin1(const int* __restrict__ hist, int k, int* __restrict__ res) {
    __shared__ int sh[1024];
    int t = threadIdx.x;
    int base = 65535 - 64 * t;
    int s = 0;
    for (int q = 0; q < 64; ++q) s += hist[base - q];
    sh[t] = s;
    __syncthreads();
    int v = s;
    for (int off = 1; off < 1024; off <<= 1) {
        int u = (t >= off) ? sh[t - off] : 0;
        __syncthreads();
        sh[t] += u;
        __syncthreads();
    }
    int before = sh[t] - v;
    if (before < k && sh[t] >= k) {
        int cum = before;
        for (int q = 0; q < 64; ++q) {
            int b = base - q;
            int hh = hist[b];
            if (cum + hh >= k) { res[0] = b; res[1] = k - cum; break; }
            cum += hh;
        }
    }
}

__global__ void k_hist2(const unsigned int* __restrict__ U, const int* __restrict__ res,
                        int* __restrict__ hist2, int N) {
    int n = blockIdx.x * 256 + threadIdx.x;
    if (n < N) {
        unsigned int u = U[n];
        if ((int)(u >> 16) == res[0]) atomicAdd(&hist2[u & 0xffff], 1);
    }
}

// ---------------- radix-select pass 2: low 16 bits ----------------
__global__ void k_findbin2(const int* __restrict__ hist, int* __restrict__ res) {
    __shared__ int sh[1024];
    int k = res[1];
    int t = threadIdx.x;
    int base = 65535 - 64 * t;
    int s = 0;
    for (int q = 0; q < 64; ++q) s += hist[base - q];
    sh[t] = s;
    __syncthreads();
    int v = s;
    for (int off = 1; off < 1024; off <<= 1) {
        int u = (t >= off) ? sh[t - off] : 0;
        __syncthreads();
        sh[t] += u;
        __syncthreads();
    }
    int before = sh[t] - v;
    if (before < k && sh[t] >= k) {
        int cum = before;
        for (int q = 0; q < 64; ++q) {
            int b = base - q;
            int hh = hist[b];
            if (cum + hh >= k) {
                res[2] = (int)(((unsigned int)res[0] << 16) | (unsigned int)b);
                res[3] = k - cum;
                break;
            }
            cum += hh;
        }
    }
}

// ---------------- selection flags (+ tie collection) ----------------
__global__ void k_flags(const unsigned int* __restrict__ U, int* __restrict__ res,
                        int* __restrict__ sel, int* __restrict__ tielist, int N) {
    int n = blockIdx.x * 256 + threadIdx.x;
    if (n >= N) return;
    unsigned int T = (unsigned int)res[2];
    unsigned int u = U[n];
    sel[n] = (u > T) ? 1 : 0;
    if (u == T) {
        int p = atomicAdd(&res[4], 1);
        if (p < 4096) tielist[p] = n;
    }
}

__global__ void k_ties(const int* __restrict__ res, int* __restrict__ tielist,
                       int* __restrict__ sel) {
    if (threadIdx.x != 0) return;
    int cnt = res[4]; if (cnt > 4096) cnt = 4096;
    int need = res[3]; if (need > cnt) need = cnt;
    for (int r = 0; r < need; ++r) {
        int mi = 0, mv = 0x7fffffff;
        for (int i = 0; i < cnt; ++i) {
            int v = tielist[i];
            if (v < mv) { mv = v; mi = i; }
        }
        sel[mv] = 1;
        tielist[mi] = 0x7fffffff;
    }
}

// ---------------- compact rows: one wave per node ----------------
__global__ __launch_bounds__(256) void k_out(const float* __restrict__ x,
        const int* __restrict__ sel, const int* __restrict__ pos,
        float* __restrict__ out, int N) {
    int wid  = (blockIdx.x * 256 + threadIdx.x) >> 6;
    int lane = threadIdx.x & 63;
    if (wid >= N) return;
    if (sel[wid]) {
        int p = pos[wid];
        ((float2*)out)[(size_t)p * 64 + lane] = ((const float2*)x)[(size_t)wid * 64 + lane];
    }
}

extern "C" void kernel_launch(void* const* d_in, const int* in_sizes, int n_in,
                              void* d_out, int out_size, void* d_ws, size_t ws_size,
                              hipStream_t stream) {
    const float* x  = (const float*)d_in[0];
    const int*   ei = (const int*)d_in[1];
    const float* W1 = (const float*)d_in[2];
    const float* b1 = (const float*)d_in[3];
    const float* W2 = (const float*)d_in[4];
    const float* b2 = (const float*)d_in[5];
    int N = in_sizes[0] / C;            // 100000
    int E = in_sizes[1] / 2;            // 800000
    int k = out_size / C;               // harness-derived k

    char* w = (char*)d_ws;
    size_t ofs = 0;
    auto alloc = [&](size_t bytes) -> char* {
        char* p = w + ofs;
        ofs += (bytes + 511) & ~(size_t)511;
        return p;
    };
    // zero-init region first (single contiguous memset)
    int*   outdeg  = (int*)alloc((size_t)N * 4);
    int*   indeg   = (int*)alloc((size_t)N * 4);
    int*   hist1   = (int*)alloc(65536 * 4);
    int*   hist2   = (int*)alloc(65536 * 4);
    int*   res     = (int*)alloc(64);
    size_t zero_bytes = ofs;
    // rest (fully overwritten before use)
    int*   offsets = (int*)alloc((size_t)(N + 1) * 4);
    int*   cursor  = (int*)alloc((size_t)N * 4);
    int*   csr     = (int*)alloc((size_t)E * 4);
    float* nsrc    = (float*)alloc((size_t)N * 4);
    float* ndst    = (float*)alloc((size_t)N * 4);
    float* g       = (float*)alloc((size_t)N * C * 4);
    float* tn      = (float*)alloc((size_t)N * 4);
    unsigned int* U = (unsigned int*)alloc((size_t)N * 4);
    int*   tielist = (int*)alloc(4096 * 4);
    int*   sel     = (int*)alloc((size_t)N * 4);
    int*   pos     = (int*)alloc((size_t)N * 4);
    int*   bsums   = (int*)alloc(1024 * 4);

    hipMemsetAsync(d_ws, 0, zero_bytes, stream);

    int nb = (N + 1023) / 1024;
    k_detect<<<16, 256, 0, stream>>>(ei, E, res);
    k_deg<<<(E + 255) / 256, 256, 0, stream>>>(ei, E, res, outdeg, indeg);
    scan1<<<nb, 1024, 0, stream>>>(indeg, offsets, bsums, N, outdeg, nsrc, ndst);
    scan2<<<1, 1024, 0, stream>>>(bsums, nb);
    scan3<<<nb, 1024, 0, stream>>>(offsets, bsums, cursor, N);
    k_csr<<<(E + 255) / 256, 256, 0, stream>>>(ei, E, res, cursor, csr);
    k_agg<<<(N + 3) / 4, 256, 0, stream>>>(x, csr, indeg, offsets, nsrc, ndst, g, N);
    k_gemm<<<(N + 127) / 128, 256, 0, stream>>>(g, W1, b1, W2, nsrc, tn, N);
    k_l2<<<(N + 255) / 256, 256, 0, stream>>>(csr, indeg, offsets, tn, ndst, b2, U, hist1, N);
    k_findbin1<<<1, 1024, 0, stream>>>(hist1, k, res);
    k_hist2<<<(N + 255) / 256, 256, 0, stream>>>(U, res, hist2, N);
    k_findbin2<<<1, 1024, 0, stream>>>(hist2, res);
    k_flags<<<(N + 255) / 256, 256, 0, stream>>>(U, res, sel, tielist, N);
    k_ties<<<1, 64, 0, stream>>>(res, tielist, sel);
    scan1<<<nb, 1024, 0, stream>>>(sel, pos, bsums, N, nullptr, nullptr, nullptr);
    scan2<<<1, 1024, 0, stream>>>(bsums, nb);
    scan3<<<nb, 1024, 0, stream>>>(pos, bsums, nullptr, N);
    k_out<<<(N + 3) / 4, 256, 0, stream>>>(x, sel, pos, (float*)d_out, N);
}